// Round 18
// baseline (39.506 us; speedup 1.0000x reference)
//
#include <hip/hip_runtime.h>
#include <hip/hip_bf16.h>
#include <math.h>

#define BM 16
#define SPAD 112            // padded sample count (100 -> 7*16)
#define NTILE 7             // 112/16 column tiles
#define NTHREADS 256

typedef __attribute__((ext_vector_type(8))) short short8;   // 8 bf16
typedef __attribute__((ext_vector_type(4))) float f32x4;

__device__ __forceinline__ unsigned short f2bfu(float f) {
    union { __hip_bfloat16 h; unsigned short u; } cv;
    cv.h = __float2bfloat16(f);
    return cv.u;
}

// Fragment-major Qb: Qb[((tile*12 + ck64)*2 + ks)*64 + lane][8 bf16]
// so a wave's B-fragment load is one contiguous 1 KB read.
__global__ void ssce_qprep(const float* __restrict__ proj,
                           const int*   __restrict__ samples,
                           unsigned short* __restrict__ Qb, int D, int S)
{
    const int t    = blockIdx.x / 12;         // tile 0..6
    const int ck   = blockIdx.x % 12;         // 64-chunk 0..11
    const int tid  = threadIdx.x;             // 0..127
    const int lane = tid & 63;
    const int ks   = tid >> 6;                // 0..1
    const int col  = lane & 15;
    const int g    = lane >> 4;

    int s   = t * 16 + col;
    int row = samples[s < S ? s : S - 1];     // clamp pads (masked in epilogue)
    const float* src = proj + (size_t)row * D + ck * 64 + ks * 32 + g * 8;
    unsigned short* dst = Qb + ((size_t)((t * 12 + ck) * 2 + ks) * 64 + lane) * 8;
    #pragma unroll
    for (int e = 0; e < 8; ++e) dst[e] = f2bfu(src[e]);
}

#define DOT4(a, b) ((a).x*(b).x + (a).y*(b).y + (a).z*(b).z + (a).w*(b).w)

#define STAGEW(BOFF, P0, P1)                                                  \
  {                                                                           \
    unsigned int u0 = (unsigned)f2bfu((P0).x) | ((unsigned)f2bfu((P0).y)<<16);\
    unsigned int u1 = (unsigned)f2bfu((P0).z) | ((unsigned)f2bfu((P0).w)<<16);\
    unsigned int u2 = (unsigned)f2bfu((P1).x) | ((unsigned)f2bfu((P1).y)<<16);\
    unsigned int u3 = (unsigned)f2bfu((P1).z) | ((unsigned)f2bfu((P1).w)<<16);\
    *(uint2*)(ldsBase + (BOFF) + wByteLo) = make_uint2(u0, u1);               \
    *(uint2*)(ldsBase + (BOFF) + wByteHi) = make_uint2(u2, u3);               \
  }

// partials[bid] = loss sum, partials[grid+bid] = valid count
__global__ __launch_bounds__(NTHREADS)
void ssce_main(const float* __restrict__ pred,
               const int*   __restrict__ labels,
               const float* __restrict__ proj,
               const float* __restrict__ bias,
               const int*   __restrict__ samples,
               const unsigned short* __restrict__ Qb,
               float* __restrict__ partials,
               int Btot, int D, int S, float logV1)
{
    // bf16 pred tile for ALL 6 K-chunks [6][16][128], XOR-swizzled: 24576 B
    __shared__ unsigned short sAb[6][BM][128];
    __shared__ float scores[BM * 113];          // 7232 B
    __shared__ float sLabelScore[BM];
    __shared__ float sBiasS[SPAD];
    __shared__ int   sSamp[SPAD];
    __shared__ int   sLabels[BM];
    __shared__ float sPt[4], sVc[4];

    const int tid  = threadIdx.x;
    const int lane = tid & 63;
    const int w    = tid >> 6;            // wave 0..3
    const int l16  = lane & 15;
    const int g    = lane >> 4;           // 0..3
    const int ctA  = 2 * w;               // col tiles {0,1},{2,3},{4,5},{6,6dup}
    const int ctB  = (w == 3) ? 6 : 2 * w + 1;
    const int rowBase = blockIdx.x * BM;

    if (tid < SPAD) {
        int s = (tid < S) ? samples[tid] : -1;
        sSamp[tid]  = s;
        sBiasS[tid] = (s >= 0) ? bias[s] : 0.0f;
    }
    if (tid < BM) {
        int gr = rowBase + tid;
        sLabels[tid] = (gr < Btot) ? labels[gr] : -100;
    }
    __syncthreads();

    // staging/label mapping: 16-lane group sr owns pred row sr
    const int sr = tid >> 4;              // 0..15
    const int li = tid & 15;              // 0..15
    const float* aSrc = pred + (size_t)min(rowBase + sr, Btot - 1) * D + li * 4;
    const int lab_sr  = sLabels[sr];
    const float lflag = (lab_sr >= 0) ? 1.0f : 0.0f;
    const float* lSrc = proj + (size_t)(lab_sr >= 0 ? lab_sr : 0) * D + li * 4;

    // swizzled LDS byte addresses (row stride 256 B = 16 units of 16 B)
    const int swz = sr & 7;
    const int wByteLo = sr * 256 + ((((li >> 1) ^ swz)     ) << 4) + ((li & 1) << 3);
    const int wByteHi = sr * 256 + ((((li >> 1) ^ swz) + 8 ) << 4) + ((li & 1) << 3);
    int rByte[4];
    #pragma unroll
    for (int ks = 0; ks < 4; ++ks)
        rByte[ks] = l16 * 256 + (((ks * 4 + g) ^ (l16 & 7)) << 4);

    // fragment-major B pointers (wave-contiguous 1 KB per load)
    const unsigned short* qA = Qb + ((size_t)(ctA * 24) * 64 + lane) * 8;
    const unsigned short* qB = Qb + ((size_t)(ctB * 24) * 64 + lane) * 8;

    f32x4 acc0 = {0.f,0.f,0.f,0.f}, acc1 = {0.f,0.f,0.f,0.f};
    float lpart = 0.0f;

    char* ldsBase = (char*)&sAb[0][0][0];

    // ================= PHASE 1: stage ALL 6 chunks, no inner barriers ======
    // 2-deep per-wave pipeline; waves slide independently (no coupling).
    {
        float4 pA0 = *(const float4*)(aSrc);
        float4 pA1 = *(const float4*)(aSrc + 64);
        float4 lA0 = *(const float4*)(lSrc);
        float4 lA1 = *(const float4*)(lSrc + 64);
        float4 pB0 = *(const float4*)(aSrc + 128);
        float4 pB1 = *(const float4*)(aSrc + 192);
        float4 lB0 = *(const float4*)(lSrc + 128);
        float4 lB1 = *(const float4*)(lSrc + 192);

        for (int c = 0; c < 6; c += 2) {
            STAGEW(c * 4096, pA0, pA1);
            lpart += DOT4(pA0, lA0) + DOT4(pA1, lA1);
            if (c + 2 < 6) {
                const int k2 = (c + 2) << 7;
                pA0 = *(const float4*)(aSrc + k2);
                pA1 = *(const float4*)(aSrc + k2 + 64);
                lA0 = *(const float4*)(lSrc + k2);
                lA1 = *(const float4*)(lSrc + k2 + 64);
            }
            STAGEW((c + 1) * 4096, pB0, pB1);
            lpart += DOT4(pB0, lB0) + DOT4(pB1, lB1);
            if (c + 3 < 6) {
                const int k3 = (c + 3) << 7;
                pB0 = *(const float4*)(aSrc + k3);
                pB1 = *(const float4*)(aSrc + k3 + 64);
                lB0 = *(const float4*)(lSrc + k3);
                lB1 = *(const float4*)(lSrc + k3 + 64);
            }
        }
    }
    __syncthreads();                      // ONE barrier: whole A-tile visible

    // ================= PHASE 2: barrier-free K-loop ========================
    const int nIt = D >> 7;               // 6 (runtime -> bounded unroll)
    for (int it = 0; it < nIt; ++it) {
        const int boff = it * 4096;
        const size_t fo = (size_t)(it * 4) * 512;   // 4 frags x 512 ushorts

        short8 bA[4], bB[4];
        #pragma unroll
        for (int ks = 0; ks < 4; ++ks) {
            bA[ks] = *(const short8*)(qA + fo + ks * 512);
            bB[ks] = *(const short8*)(qB + fo + ks * 512);
        }
        #pragma unroll
        for (int ks = 0; ks < 4; ++ks) {
            short8 a8 = *(const short8*)(ldsBase + boff + rByte[ks]);
            acc0 = __builtin_amdgcn_mfma_f32_16x16x32_bf16(a8, bA[ks], acc0, 0, 0, 0);
            acc1 = __builtin_amdgcn_mfma_f32_16x16x32_bf16(a8, bB[ks], acc1, 0, 0, 0);
        }
    }

    // reduce label dot within each 16-lane group
    lpart *= lflag;
    lpart += __shfl_down(lpart, 8, 16);
    lpart += __shfl_down(lpart, 4, 16);
    lpart += __shfl_down(lpart, 2, 16);
    lpart += __shfl_down(lpart, 1, 16);
    if (li == 0)
        sLabelScore[sr] = (lab_sr >= 0) ? (lpart + bias[lab_sr]) : 0.0f;

    // scores -> LDS (C-layout: col = lane&15, row = g*4 + i)
    #pragma unroll
    for (int i = 0; i < 4; ++i) {
        int row = g * 4 + i;
        scores[row * 113 + ctA * 16 + l16] = acc0[i];
        scores[row * 113 + ctB * 16 + l16] = acc1[i];   // w=3 dup write: same val
    }
    __syncthreads();

    // ---- wave-parallel softmax CE: group sr handles row sr, 7 slots/lane ----
    const int  row   = sr;
    const int  lab   = lab_sr;
    const bool valid = (lab != -100) && (rowBase + row < Btot);

    int cnt = 0;
    #pragma unroll
    for (int k = 0; k < 7; ++k) {
        int s = li + 16 * k;
        if (s < S) cnt += (sSamp[s] == lab) ? 1 : 0;
    }
    cnt += __shfl_xor(cnt, 1, 16);
    cnt += __shfl_xor(cnt, 2, 16);
    cnt += __shfl_xor(cnt, 4, 16);
    cnt += __shfl_xor(cnt, 8, 16);

    const float corr = logV1 - __logf((float)(S - cnt));
    const float ls   = sLabelScore[row];

    float v7[7];
    float mv = -1e30f;
    #pragma unroll
    for (int k = 0; k < 7; ++k) {
        int s = li + 16 * k;
        float v = -1e30f;
        if (s < S) {
            v = scores[row * 113 + s] + sBiasS[s] + corr;
            if (valid && sSamp[s] == lab) v -= 1000000.0f;
        }
        v7[k] = v;
        mv = fmaxf(mv, v);
    }
    mv = fmaxf(mv, __shfl_xor(mv, 1, 16));
    mv = fmaxf(mv, __shfl_xor(mv, 2, 16));
    mv = fmaxf(mv, __shfl_xor(mv, 4, 16));
    mv = fmaxf(mv, __shfl_xor(mv, 8, 16));
    const float m = fmaxf(mv, ls);

    float se = 0.0f;
    #pragma unroll
    for (int k = 0; k < 7; ++k)
        se += __expf(v7[k] - m);          // -1e30 pads underflow to 0
    se += __shfl_xor(se, 1, 16);
    se += __shfl_xor(se, 2, 16);
    se += __shfl_xor(se, 4, 16);
    se += __shfl_xor(se, 8, 16);

    float pt = 0.0f, vc = 0.0f;
    if (li == 0 && valid) {
        float set = se + __expf(ls - m);
        pt = m - ls + __logf(set);
        vc = 1.0f;
    }
    pt += __shfl_down(pt, 16); vc += __shfl_down(vc, 16);
    pt += __shfl_down(pt, 32); vc += __shfl_down(vc, 32);
    if (lane == 0) { sPt[w] = pt; sVc[w] = vc; }
    __syncthreads();
    if (tid == 0) {
        partials[blockIdx.x]             = sPt[0] + sPt[1] + sPt[2] + sPt[3];
        partials[gridDim.x + blockIdx.x] = sVc[0] + sVc[1] + sVc[2] + sVc[3];
    }
}

__global__ void ssce_final(const float* __restrict__ partials, int nb,
                           float* __restrict__ out)
{
    __shared__ float red[8];
    int tid = threadIdx.x;
    float s = 0.0f, c = 0.0f;
    for (int i = tid; i < nb; i += 256) {
        s += partials[i];
        c += partials[nb + i];
    }
    #pragma unroll
    for (int off = 32; off > 0; off >>= 1) {
        s += __shfl_down(s, off);
        c += __shfl_down(c, off);
    }
    int wv = tid >> 6;
    if ((tid & 63) == 0) { red[wv * 2] = s; red[wv * 2 + 1] = c; }
    __syncthreads();
    if (tid == 0) {
        float S2 = 0.0f, C2 = 0.0f;
        for (int i = 0; i < 4; ++i) { S2 += red[i * 2]; C2 += red[i * 2 + 1]; }
        out[0] = S2 / fmaxf(C2, 1.0f);
    }
}

extern "C" void kernel_launch(void* const* d_in, const int* in_sizes, int n_in,
                              void* d_out, int out_size, void* d_ws, size_t ws_size,
                              hipStream_t stream)
{
    const float* pred    = (const float*)d_in[0];
    const int*   labels  = (const int*)  d_in[1];
    const float* proj    = (const float*)d_in[2];
    const float* bias    = (const float*)d_in[3];
    const int*   samples = (const int*)  d_in[4];

    const int B = in_sizes[1];
    const int V = in_sizes[3];
    const int S = in_sizes[4];
    const int D = in_sizes[0] / B;        // 768

    float logV1 = logf((float)(V - 1));
    float* partials = (float*)d_ws;                              // 2*grid floats
    unsigned short* Qb = (unsigned short*)((char*)d_ws + 32768);

    ssce_qprep<<<NTILE * 12, 128, 0, stream>>>(proj, samples, Qb, D, S);

    const int grid = (B + BM - 1) / BM;   // 1024 -> 4 blocks/CU
    ssce_main<<<grid, NTHREADS, 0, stream>>>(pred, labels, proj, bias, samples,
                                             Qb, partials, B, D, S, logV1);
    ssce_final<<<1, 256, 0, stream>>>(partials, grid, (float*)d_out);
}

// Round 19
// 32.546 us; speedup vs baseline: 1.2138x; 1.2138x over previous
//
#include <hip/hip_runtime.h>
#include <hip/hip_bf16.h>
#include <math.h>

#define BM 16
#define SPAD 112            // padded sample count (100 -> 7*16)
#define NTILE 7             // 112/16 column tiles
#define NTHREADS 256
#define NIT 6               // D=768 -> 6 iterations of BK=128 (hardcoded)

typedef __attribute__((ext_vector_type(8))) short short8;   // 8 bf16
typedef __attribute__((ext_vector_type(4))) float f32x4;

__device__ __forceinline__ unsigned short f2bfu(float f) {
    union { __hip_bfloat16 h; unsigned short u; } cv;
    cv.h = __float2bfloat16(f);
    return cv.u;
}

// Fragment-major Qb: Qb[((tile*12 + ck64)*2 + ks)*64 + lane][8 bf16]
// so a wave's B-fragment load is one contiguous 1 KB read.
__global__ void ssce_qprep(const float* __restrict__ proj,
                           const int*   __restrict__ samples,
                           unsigned short* __restrict__ Qb, int D, int S)
{
    const int t    = blockIdx.x / 12;         // tile 0..6
    const int ck   = blockIdx.x % 12;         // 64-chunk 0..11
    const int tid  = threadIdx.x;             // 0..127
    const int lane = tid & 63;
    const int ks   = tid >> 6;                // 0..1
    const int col  = lane & 15;
    const int g    = lane >> 4;

    int s   = t * 16 + col;
    int row = samples[s < S ? s : S - 1];     // clamp pads (masked in epilogue)
    const float* src = proj + (size_t)row * D + ck * 64 + ks * 32 + g * 8;
    unsigned short* dst = Qb + ((size_t)((t * 12 + ck) * 2 + ks) * 64 + lane) * 8;
    #pragma unroll
    for (int e = 0; e < 8; ++e) dst[e] = f2bfu(src[e]);
}

#define DOT4(a, b) ((a).x*(b).x + (a).y*(b).y + (a).z*(b).z + (a).w*(b).w)

// partials[bid] = loss sum, partials[grid+bid] = valid count
__global__ __launch_bounds__(NTHREADS)
void ssce_main(const float* __restrict__ pred,
               const int*   __restrict__ labels,
               const float* __restrict__ proj,
               const float* __restrict__ bias,
               const int*   __restrict__ samples,
               const unsigned short* __restrict__ Qb,
               float* __restrict__ partials,
               int Btot, int D, int S, float logV1)
{
    // bf16 pred tile [16][128], double-buffered, XOR-swizzled 16B units: 8192 B
    __shared__ unsigned short sAb[2][BM][128];
    __shared__ float scores[BM * 113];          // 7232 B
    __shared__ float sLabelScore[BM];
    __shared__ float sBiasS[SPAD];
    __shared__ int   sSamp[SPAD];
    __shared__ int   sLabels[BM];
    __shared__ float sPt[4], sVc[4];

    const int tid  = threadIdx.x;
    const int lane = tid & 63;
    const int w    = tid >> 6;            // wave 0..3
    const int l16  = lane & 15;
    const int g    = lane >> 4;           // 0..3
    const int ctA  = 2 * w;               // col tiles {0,1},{2,3},{4,5},{6,6dup}
    const int ctB  = (w == 3) ? 6 : 2 * w + 1;
    const int rowBase = blockIdx.x * BM;

    if (tid < SPAD) {
        int s = (tid < 100) ? samples[tid] : -1;
        sSamp[tid]  = s;
        sBiasS[tid] = (s >= 0) ? bias[s] : 0.0f;
    }
    if (tid < BM) {
        int gr = rowBase + tid;
        sLabels[tid] = (gr < Btot) ? labels[gr] : -100;
    }
    __syncthreads();

    // group mapping: 16-lane group sr owns pred row sr
    const int sr = tid >> 4;              // 0..15
    const int li = tid & 15;              // 0..15
    const float* aSrc = pred + (size_t)min(rowBase + sr, Btot - 1) * 768 + li * 4;
    const int lab_sr  = sLabels[sr];
    const float lflag = (lab_sr >= 0) ? 1.0f : 0.0f;
    const float* lSrc = proj + (size_t)(lab_sr >= 0 ? lab_sr : 0) * 768 + li * 4;

    // swizzled LDS byte addresses (row stride 256 B = 16 units of 16 B)
    const int swz = sr & 7;
    const int wByteLo = sr * 256 + ((((li >> 1) ^ swz)     ) << 4) + ((li & 1) << 3);
    const int wByteHi = sr * 256 + ((((li >> 1) ^ swz) + 8 ) << 4) + ((li & 1) << 3);
    int rByte[4];
    #pragma unroll
    for (int ks = 0; ks < 4; ++ks)
        rByte[ks] = l16 * 256 + (((ks * 4 + g) ^ (l16 & 7)) << 4);

    // fragment-major B pointers (wave-contiguous 1 KB per load)
    const unsigned short* qA = Qb + ((size_t)(ctA * 24) * 64 + lane) * 8;
    const unsigned short* qB = Qb + ((size_t)(ctB * 24) * 64 + lane) * 8;

    f32x4 acc0 = {0.f,0.f,0.f,0.f}, acc1 = {0.f,0.f,0.f,0.f};
    float lpart = 0.0f;

    char* ldsBase = (char*)&sAb[0][0][0];

    // 1-ahead register prefetch (16 VGPR): pred + proj[label] rows
    float4 pf0 = *(const float4*)(aSrc);
    float4 pf1 = *(const float4*)(aSrc + 64);
    float4 pl0 = *(const float4*)(lSrc);
    float4 pl1 = *(const float4*)(lSrc + 64);

    #pragma unroll
    for (int it = 0; it < NIT; ++it) {
        const int boff = (it & 1) * 4096;  // buffer stride: 16 rows x 256 B

        // pack current pred chunk to bf16, store swizzled (2 x 8 B)
        unsigned int u0 = (unsigned)f2bfu(pf0.x) | ((unsigned)f2bfu(pf0.y) << 16);
        unsigned int u1 = (unsigned)f2bfu(pf0.z) | ((unsigned)f2bfu(pf0.w) << 16);
        unsigned int u2 = (unsigned)f2bfu(pf1.x) | ((unsigned)f2bfu(pf1.y) << 16);
        unsigned int u3 = (unsigned)f2bfu(pf1.z) | ((unsigned)f2bfu(pf1.w) << 16);
        *(uint2*)(ldsBase + boff + wByteLo) = make_uint2(u0, u1);
        *(uint2*)(ldsBase + boff + wByteHi) = make_uint2(u2, u3);

        // label dot with CURRENT chunk (exact f32, from registers)
        lpart += DOT4(pf0, pl0) + DOT4(pf1, pl1);

        // prefetch NEXT iteration BEFORE the barrier (global reads only; the
        // barrier is a scheduling fence, so issuing here buys the HBM load
        // the barrier-wait time as extra latency slack)
        if (it + 1 < NIT) {
            const int kn = (it + 1) << 7;
            pf0 = *(const float4*)(aSrc + kn);
            pf1 = *(const float4*)(aSrc + kn + 64);
            pl0 = *(const float4*)(lSrc + kn);
            pl1 = *(const float4*)(lSrc + kn + 64);
        }

        __syncthreads();                  // tile visible; other buffer free

        // B fragments: 8 contiguous 1 KB wave loads (L2-resident);
        // offsets are compile-time constants after full unroll
        const int fo = it * 2048;          // 4 frags x 512 ushorts
        short8 bA[4], bB[4];
        #pragma unroll
        for (int ks = 0; ks < 4; ++ks) {
            bA[ks] = *(const short8*)(qA + fo + ks * 512);
            bB[ks] = *(const short8*)(qB + fo + ks * 512);
        }

        // A fragments (ds_read_b128) + MFMA, 4 K-steps of 32
        #pragma unroll
        for (int ks = 0; ks < 4; ++ks) {
            short8 a8 = *(const short8*)(ldsBase + boff + rByte[ks]);
            acc0 = __builtin_amdgcn_mfma_f32_16x16x32_bf16(a8, bA[ks], acc0, 0, 0, 0);
            acc1 = __builtin_amdgcn_mfma_f32_16x16x32_bf16(a8, bB[ks], acc1, 0, 0, 0);
        }
    }

    // reduce label dot within each 16-lane group
    lpart *= lflag;
    lpart += __shfl_down(lpart, 8, 16);
    lpart += __shfl_down(lpart, 4, 16);
    lpart += __shfl_down(lpart, 2, 16);
    lpart += __shfl_down(lpart, 1, 16);
    if (li == 0)
        sLabelScore[sr] = (lab_sr >= 0) ? (lpart + bias[lab_sr]) : 0.0f;

    // scores -> LDS (C-layout: col = lane&15, row = g*4 + i)
    #pragma unroll
    for (int i = 0; i < 4; ++i) {
        int row = g * 4 + i;
        scores[row * 113 + ctA * 16 + l16] = acc0[i];
        scores[row * 113 + ctB * 16 + l16] = acc1[i];   // w=3 dup write: same val
    }
    __syncthreads();

    // ---- wave-parallel softmax CE: group sr handles row sr, 7 slots/lane ----
    const int  row   = sr;
    const int  lab   = lab_sr;
    const bool valid = (lab != -100) && (rowBase + row < Btot);

    int cnt = 0;
    #pragma unroll
    for (int k = 0; k < 7; ++k) {
        int s = li + 16 * k;
        if (s < 100) cnt += (sSamp[s] == lab) ? 1 : 0;
    }
    cnt += __shfl_xor(cnt, 1, 16);
    cnt += __shfl_xor(cnt, 2, 16);
    cnt += __shfl_xor(cnt, 4, 16);
    cnt += __shfl_xor(cnt, 8, 16);

    const float corr = logV1 - __logf((float)(100 - cnt));
    const float ls   = sLabelScore[row];

    float v7[7];
    float mv = -1e30f;
    #pragma unroll
    for (int k = 0; k < 7; ++k) {
        int s = li + 16 * k;
        float v = -1e30f;
        if (s < 100) {
            v = scores[row * 113 + s] + sBiasS[s] + corr;
            if (valid && sSamp[s] == lab) v -= 1000000.0f;
        }
        v7[k] = v;
        mv = fmaxf(mv, v);
    }
    mv = fmaxf(mv, __shfl_xor(mv, 1, 16));
    mv = fmaxf(mv, __shfl_xor(mv, 2, 16));
    mv = fmaxf(mv, __shfl_xor(mv, 4, 16));
    mv = fmaxf(mv, __shfl_xor(mv, 8, 16));
    const float m = fmaxf(mv, ls);

    float se = 0.0f;
    #pragma unroll
    for (int k = 0; k < 7; ++k)
        se += __expf(v7[k] - m);          // -1e30 pads underflow to 0
    se += __shfl_xor(se, 1, 16);
    se += __shfl_xor(se, 2, 16);
    se += __shfl_xor(se, 4, 16);
    se += __shfl_xor(se, 8, 16);

    float pt = 0.0f, vc = 0.0f;
    if (li == 0 && valid) {
        float set = se + __expf(ls - m);
        pt = m - ls + __logf(set);
        vc = 1.0f;
    }
    pt += __shfl_down(pt, 16); vc += __shfl_down(vc, 16);
    pt += __shfl_down(pt, 32); vc += __shfl_down(vc, 32);
    if (lane == 0) { sPt[w] = pt; sVc[w] = vc; }
    __syncthreads();
    if (tid == 0) {
        partials[blockIdx.x]             = sPt[0] + sPt[1] + sPt[2] + sPt[3];
        partials[gridDim.x + blockIdx.x] = sVc[0] + sVc[1] + sVc[2] + sVc[3];
    }
}

__global__ void ssce_final(const float* __restrict__ partials, int nb,
                           float* __restrict__ out)
{
    __shared__ float red[8];
    int tid = threadIdx.x;
    float s = 0.0f, c = 0.0f;
    for (int i = tid; i < nb; i += 256) {
        s += partials[i];
        c += partials[nb + i];
    }
    #pragma unroll
    for (int off = 32; off > 0; off >>= 1) {
        s += __shfl_down(s, off);
        c += __shfl_down(c, off);
    }
    int wv = tid >> 6;
    if ((tid & 63) == 0) { red[wv * 2] = s; red[wv * 2 + 1] = c; }
    __syncthreads();
    if (tid == 0) {
        float S2 = 0.0f, C2 = 0.0f;
        for (int i = 0; i < 4; ++i) { S2 += red[i * 2]; C2 += red[i * 2 + 1]; }
        out[0] = S2 / fmaxf(C2, 1.0f);
    }
}

extern "C" void kernel_launch(void* const* d_in, const int* in_sizes, int n_in,
                              void* d_out, int out_size, void* d_ws, size_t ws_size,
                              hipStream_t stream)
{
    const float* pred    = (const float*)d_in[0];
    const int*   labels  = (const int*)  d_in[1];
    const float* proj    = (const float*)d_in[2];
    const float* bias    = (const float*)d_in[3];
    const int*   samples = (const int*)  d_in[4];

    const int B = in_sizes[1];
    const int V = in_sizes[3];
    const int S = in_sizes[4];
    const int D = in_sizes[0] / B;        // 768

    float logV1 = logf((float)(V - 1));
    float* partials = (float*)d_ws;                              // 2*grid floats
    unsigned short* Qb = (unsigned short*)((char*)d_ws + 32768);

    ssce_qprep<<<NTILE * 12, 128, 0, stream>>>(proj, samples, Qb, D, S);

    const int grid = (B + BM - 1) / BM;   // 1024 -> 4 blocks/CU
    ssce_main<<<grid, NTHREADS, 0, stream>>>(pred, labels, proj, bias, samples,
                                             Qb, partials, B, D, S, logV1);
    ssce_final<<<1, 256, 0, stream>>>(partials, grid, (float*)d_out);
}